// Round 2
// baseline (212.370 us; speedup 1.0000x reference)
//
#include <hip/hip_runtime.h>
#include <math.h>

#define DT_F      0.1f
#define PI_F      3.14159265358979323846f
#define TWO_PI_F  6.28318530717958647692f
// exp(-8.0) precomputed
#define EXP_M8_F  0.00033546262790251185f

__global__ __launch_bounds__(256) void belief_step_kernel(
    const float* __restrict__ x,
    const float* __restrict__ P,
    const float* __restrict__ a,
    const float* __restrict__ th,
    float* __restrict__ out_x,
    float* __restrict__ out_P)
{
    // LDS staging: inputs first, buffers reused for outputs after barrier.
    __shared__ float s_x[768];    // 256 * 3
    __shared__ float s_P[2304];   // 256 * 9
    __shared__ float s_a[512];    // 256 * 2
    __shared__ float s_th[768];   // 256 * 3

    const int tid = threadIdx.x;
    const long long base = (long long)blockIdx.x * 256;

    // ---- cooperative, fully-coalesced float4 global->LDS staging ----
    const float4* gx = (const float4*)(x  + base * 3);
    const float4* gP = (const float4*)(P  + base * 9);
    const float4* ga = (const float4*)(a  + base * 2);
    const float4* gt = (const float4*)(th + base * 3);
    float4* s_x4 = (float4*)s_x;
    float4* s_P4 = (float4*)s_P;
    float4* s_a4 = (float4*)s_a;
    float4* s_t4 = (float4*)s_th;

    s_P4[tid]       = gP[tid];          // 576 float4 total for P
    s_P4[tid + 256] = gP[tid + 256];
    if (tid < 64)  s_P4[tid + 512] = gP[tid + 512];
    if (tid < 192) { s_x4[tid] = gx[tid]; s_t4[tid] = gt[tid]; }
    if (tid < 128) s_a4[tid] = ga[tid];

    __syncthreads();

    // ---- per-thread gather from LDS (stride 3/9 -> 2-way alias, free) ----
    const float px  = s_x[tid * 3 + 0];
    const float py  = s_x[tid * 3 + 1];
    const float ang = s_x[tid * 3 + 2];
    const float a0  = s_a[tid * 2 + 0];
    const float a1  = s_a[tid * 2 + 1];
    const float t0  = s_th[tid * 3 + 0];
    const float t1  = s_th[tid * 3 + 1];
    const float t2  = s_th[tid * 3 + 2];
    float Pm[9];
    #pragma unroll
    for (int j = 0; j < 9; ++j) Pm[j] = s_P[tid * 9 + j];

    __syncthreads();   // all reads done; LDS can be overwritten with outputs

    // ---- compute (registers only) ----
    // range_angle(ang - theta1*a1*DT)
    const float ar   = ang - t1 * a1 * DT_F;
    const float ang_ = ar - TWO_PI_F * floorf((ar + PI_F) / TWO_PI_F);
    float s, c;
    sincosf(ang_, &s, &c);
    const float v = t0 * a0 * DT_F;

    float px_ = px + v * c;
    float py_ = py + v * s;
    px_ = fminf(fmaxf(px_, -1.0f), 1.0f);
    py_ = fminf(fmaxf(py_, -1.0f), 1.0f);

    // A = [[1,0,w0],[0,1,w1],[0,0,1]],  w0 = -v*s, w1 = v*c
    const float w0 = -v * s;
    const float w1 =  v * c;

    // AP = A @ P : row0 = P.row0 + w0*P.row2 ; row1 = P.row1 + w1*P.row2 ; row2 = P.row2
    float AP0[3], AP1[3], AP2[3];
    #pragma unroll
    for (int k = 0; k < 3; ++k) {
        AP0[k] = fmaf(w0, Pm[6 + k], Pm[0 + k]);
        AP1[k] = fmaf(w1, Pm[6 + k], Pm[3 + k]);
        AP2[k] = Pm[6 + k];
    }

    // M = AP @ A^T : col0 = AP.col0 + w0*AP.col2 ; col1 = AP.col1 + w1*AP.col2 ; col2 = AP.col2
    float M00 = fmaf(w0, AP0[2], AP0[0]);
    float M01 = fmaf(w1, AP0[2], AP0[1]);
    float M02 = AP0[2];
    float M10 = fmaf(w0, AP1[2], AP1[0]);
    float M11 = fmaf(w1, AP1[2], AP1[1]);
    float M12 = AP1[2];
    float M20 = fmaf(w0, AP2[2], AP2[0]);
    float M21 = fmaf(w1, AP2[2], AP2[1]);
    float M22 = AP2[2];

    // + diag(exp(2*t2), exp(2*t2), exp(-8))
    const float q01 = expf(2.0f * t2);
    M00 += q01;
    M11 += q01;
    M22 += EXP_M8_F;

    // symmetrize + 1e-6 * I
    const float S00 = M00 + 1e-6f;
    const float S11 = M11 + 1e-6f;
    const float S22 = M22 + 1e-6f;
    const float S01 = 0.5f * (M01 + M10);
    const float S02 = 0.5f * (M02 + M20);
    const float S12 = 0.5f * (M12 + M21);

    // ---- scatter outputs to LDS ----
    s_x[tid * 3 + 0] = px_;
    s_x[tid * 3 + 1] = py_;
    s_x[tid * 3 + 2] = ang_;
    s_P[tid * 9 + 0] = S00;
    s_P[tid * 9 + 1] = S01;
    s_P[tid * 9 + 2] = S02;
    s_P[tid * 9 + 3] = S01;
    s_P[tid * 9 + 4] = S11;
    s_P[tid * 9 + 5] = S12;
    s_P[tid * 9 + 6] = S02;
    s_P[tid * 9 + 7] = S12;
    s_P[tid * 9 + 8] = S22;

    __syncthreads();

    // ---- coalesced float4 LDS->global stores ----
    float4* ox4 = (float4*)(out_x + base * 3);
    float4* oP4 = (float4*)(out_P + base * 9);
    oP4[tid]       = s_P4[tid];
    oP4[tid + 256] = s_P4[tid + 256];
    if (tid < 64)  oP4[tid + 512] = s_P4[tid + 512];
    if (tid < 192) ox4[tid] = s_x4[tid];
}

extern "C" void kernel_launch(void* const* d_in, const int* in_sizes, int n_in,
                              void* d_out, int out_size, void* d_ws, size_t ws_size,
                              hipStream_t stream) {
    const float* x  = (const float*)d_in[0];   // (B,3)
    const float* P  = (const float*)d_in[1];   // (B,3,3)
    const float* a  = (const float*)d_in[2];   // (B,2)
    const float* th = (const float*)d_in[3];   // (B,3)

    const long long B = (long long)in_sizes[0] / 3;   // 2097152
    float* out_x = (float*)d_out;               // (B,3) first in tuple
    float* out_P = (float*)d_out + B * 3;       // (B,3,3) second

    const int nblk = (int)(B / 256);            // B is a multiple of 256
    belief_step_kernel<<<nblk, 256, 0, stream>>>(x, P, a, th, out_x, out_P);
}